// Round 7
// baseline (398.514 us; speedup 1.0000x reference)
//
#include <hip/hip_runtime.h>
#include <hip/hip_bf16.h>

typedef __attribute__((ext_vector_type(8))) short short8;
typedef __attribute__((ext_vector_type(4))) float f32x4;

#define BM 128
#define BN 256
#define BK 64
#define KDIM 7168
#define NDIM 18432
#define SN 56            // KDIM/128 scale cols
#define NTK 112          // KDIM/BK

static __device__ __forceinline__ short bfb(float f) {
    __hip_bfloat16 h = __float2bfloat16(f);
    return __builtin_bit_cast(short, h);
}

// ---- pre-kernel: A fp32 -> bf16, tile-major, inverse-XOR-swizzled so the
// GEMM can global_load_lds it linearly and read with the XOR formula.
// unit g = ((mt*NTK + kt)*1024 + r*8 + slot); content = A[mt*128+r][kt*64 + (slot^(r&7))*8 .. +8)
extern "C" __global__ void __launch_bounds__(256)
a_permute(const float* __restrict__ A, __hip_bfloat16* __restrict__ Abt, int nunits) {
    int g = blockIdx.x * blockDim.x + threadIdx.x;
    if (g >= nunits) return;
    int u    = g & 1023;
    int t    = g >> 10;
    int ktt  = t % NTK;
    int mt   = t / NTK;
    int r    = u >> 3;
    int slot = u & 7;
    int row  = mt * BM + r;
    int col  = ktt * BK + ((slot ^ (r & 7)) << 3);
    const float* p = A + (size_t)row * KDIM + col;
    f32x4 v0 = *(const f32x4*)p;
    f32x4 v1 = *(const f32x4*)(p + 4);
    short8 o;
#pragma unroll
    for (int j = 0; j < 4; ++j) { o[j] = bfb(v0[j]); o[j + 4] = bfb(v1[j]); }
    *(short8*)(Abt + (size_t)g * 8) = o;
}

// AMODE 1: A via global_load_lds from pre-permuted Abt.
// AMODE 0: fallback, A fp32 reg-staged.
template <int AMODE>
__global__ void __launch_bounds__(512, 1)
fp8lin_gemm(const float* __restrict__ A,          // [M][K] fp32
            const char*  __restrict__ Abt,        // pre-permuted bf16 tiles (ws)
            const float* __restrict__ W,          // [N][K] fp32
            const float* __restrict__ S,          // [N/128][K/128]
            float* __restrict__ C,                // [M][N]
            int M)
{
    const int ntile_m = M / BM;            // 4
    const int ntile_n = NDIM / BN;         // 72
    const int nwg = ntile_m * ntile_n;     // 288 (multiple of 8)

    // chunked XCD swizzle; m-minor so the 4 blocks sharing a W panel sit on
    // the same XCD's L2.
    int orig = (int)blockIdx.x;
    int q = nwg >> 3;                      // 36
    int lid = (orig & 7) * q + (orig >> 3);

    const int tm = lid % ntile_m;
    const int tn = lid / ntile_m;
    const int m0 = tm * BM;
    const int n0 = tn * BN;

    const int tid  = threadIdx.x;
    const int lane = tid & 63;
    const int wid  = tid >> 6;      // 8 waves: 2(M) x 4(N), wave tile 64x64
    const int wm   = wid >> 2;
    const int wn   = wid & 3;

    __shared__ char ldsA[2][BM * BK * 2];   // 16 KiB each
    __shared__ char ldsW[2][BN * BK * 2];   // 32 KiB each  (total 96 KiB)

    // W staging geometry: 2048 16B units; u = c*512 + tid (c=0..3)
    int wst_r[4], wst_sl[4], wst_byte[4];
#pragma unroll
    for (int c = 0; c < 4; ++c) {
        int u = c * 512 + tid;
        int r  = u >> 3;                   // 0..255
        int sl = u & 7;
        wst_r[c]    = r;
        wst_sl[c]   = sl;
        wst_byte[c] = r * (BK * 2) + ((sl ^ (r & 7)) << 4);
    }
    // A staging geometry (AMODE 0): 1024 units; u = c*512 + tid (c=0..1)
    int ast_r[2], ast_sl[2], ast_byte[2];
#pragma unroll
    for (int c = 0; c < 2; ++c) {
        int u = c * 512 + tid;
        int r  = u >> 3;                   // 0..127
        int sl = u & 7;
        ast_r[c]    = r;
        ast_sl[c]   = sl;
        ast_byte[c] = r * (BK * 2) + ((sl ^ (r & 7)) << 4);
    }

    const float* Afp = A + (size_t)m0 * KDIM;
    const float* Wb  = W + (size_t)n0 * KDIM;

    f32x4 rw[4][2];        // W fp32 staging (distance-2 prefetch)
    f32x4 rafp[2][2];      // A fp32 staging (AMODE 0 only)

    auto AGL = [&](int kt_, int buf) {   // async A: global -> LDS, 2 insts/wave
        const char* src = Abt + (((size_t)(tm * NTK + kt_)) << 14);
#pragma unroll
        for (int c = 0; c < 2; ++c) {
            int ub = wid * 128 + c * 64;
            __builtin_amdgcn_global_load_lds(
                (const __attribute__((address_space(1))) void*)(src + (size_t)(ub + lane) * 16),
                (__attribute__((address_space(3))) void*)(&ldsA[buf][ub * 16]),
                16, 0, 0);
        }
    };

    auto WLD = [&](int kt_) {            // W fp32 -> regs (8 x dwordx4)
        const int kof = kt_ * BK;
#pragma unroll
        for (int c = 0; c < 4; ++c) {
            const float* pw = Wb + (size_t)wst_r[c] * KDIM + kof + wst_sl[c] * 8;
            rw[c][0] = *(const f32x4*)pw;
            rw[c][1] = *(const f32x4*)(pw + 4);
        }
    };

    auto ALD = [&](int kt_) {            // AMODE 0: A fp32 -> regs
        const int kof = kt_ * BK;
#pragma unroll
        for (int c = 0; c < 2; ++c) {
            const float* pa = Afp + (size_t)ast_r[c] * KDIM + kof + ast_sl[c] * 8;
            rafp[c][0] = *(const f32x4*)pa;
            rafp[c][1] = *(const f32x4*)(pa + 4);
        }
    };

    // s0 = scale for n-rows 0..127 of this block, s1 for 128..255
    auto WRITES = [&](int buf, float s0, float s1) {
#pragma unroll
        for (int c = 0; c < 4; ++c) {
            const float sc = (wst_r[c] & 128) ? s1 : s0;
            short8 vw;
#pragma unroll
            for (int j = 0; j < 4; ++j) {
                vw[j]     = bfb(rw[c][0][j] * sc);
                vw[j + 4] = bfb(rw[c][1][j] * sc);
            }
            *(short8*)(&ldsW[buf][wst_byte[c]]) = vw;
        }
        if (AMODE == 0) {
#pragma unroll
            for (int c = 0; c < 2; ++c) {
                short8 va;
#pragma unroll
                for (int j = 0; j < 4; ++j) {
                    va[j]     = bfb(rafp[c][0][j]);
                    va[j + 4] = bfb(rafp[c][1][j]);
                }
                *(short8*)(&ldsA[buf][ast_byte[c]]) = va;
            }
        }
    };

    f32x4 acc[4][4];
#pragma unroll
    for (int i = 0; i < 4; ++i)
#pragma unroll
        for (int j = 0; j < 4; ++j)
            acc[i][j] = f32x4{0.f, 0.f, 0.f, 0.f};

    const int l15 = lane & 15;
    const int lq  = lane >> 4;

    auto COMPUTE = [&](int buf) {
        const char* la = ldsA[buf];
        const char* lb = ldsW[buf];
#pragma unroll
        for (int kk = 0; kk < 2; ++kk) {
            int kc = kk * 4 + lq;           // 16B chunk index along K
            short8 af[4], bq[4];
#pragma unroll
            for (int i = 0; i < 4; ++i) {
                int r = wm * 64 + i * 16 + l15;
                af[i] = *(const short8*)(la + r * (BK * 2) + ((kc ^ (r & 7)) << 4));
            }
#pragma unroll
            for (int j = 0; j < 4; ++j) {
                int r = wn * 64 + j * 16 + l15;
                bq[j] = *(const short8*)(lb + r * (BK * 2) + ((kc ^ (r & 7)) << 4));
            }
#pragma unroll
            for (int i = 0; i < 4; ++i)
#pragma unroll
                for (int j = 0; j < 4; ++j)
                    acc[i][j] = __builtin_amdgcn_mfma_f32_16x16x32_bf16(af[i], bq[j], acc[i][j], 0, 0, 0);
        }
    };

    // BN=256 spans two scale rows: 2*tn and 2*tn+1
    const float* Sr0 = S + (size_t)(2 * tn) * SN;
    const float* Sr1 = Sr0 + SN;

    // ---- prologue
    if (AMODE) AGL(0, 0); else ALD(0);
    WLD(0);
    WRITES(0, Sr0[0], Sr1[0]);
    if (AMODE == 0) ALD(1);
    WLD(1);
    __syncthreads();

    // ---- main loop: 2-phase double-buffer, distance-2 W prefetch
    for (int kt = 0; kt < NTK; ++kt) {
        const int cur = kt & 1;
        const int nxt = cur ^ 1;
        if (AMODE && kt + 1 < NTK) AGL(kt + 1, nxt);
        COMPUTE(cur);
        if (kt + 1 < NTK) {
            const int si = (kt + 1) >> 1;
            WRITES(nxt, Sr0[si], Sr1[si]);
            if (kt + 2 < NTK) { if (AMODE == 0) ALD(kt + 2); WLD(kt + 2); }
        }
        __syncthreads();
    }

    // ---- epilogue: 16x16 C/D layout col=lane&15, row=(lane>>4)*4+r
    float* Cb = C + (size_t)(m0 + wm * 64) * NDIM + (n0 + wn * 64);
    const int crow = lq * 4;
#pragma unroll
    for (int i = 0; i < 4; ++i) {
#pragma unroll
        for (int r = 0; r < 4; ++r) {
            float* Cr = Cb + (size_t)(i * 16 + crow + r) * NDIM + l15;
#pragma unroll
            for (int j = 0; j < 4; ++j)
                Cr[j * 16] = acc[i][j][r];
        }
    }
}

extern "C" void kernel_launch(void* const* d_in, const int* in_sizes, int n_in,
                              void* d_out, int out_size, void* d_ws, size_t ws_size,
                              hipStream_t stream) {
    const float* inp = (const float*)d_in[0];   // [1,512,7168] fp32
    const float* w   = (const float*)d_in[1];   // [18432,7168] fp32
    const float* s   = (const float*)d_in[2];   // [144,56] fp32
    float* out       = (float*)d_out;           // [1,512,18432] fp32

    int M = in_sizes[0] / KDIM;                 // 512
    int grid = (M / BM) * (NDIM / BN);          // 288
    int nunits = (M / BM) * NTK * 1024;
    size_t need = (size_t)nunits * 16;

    if (ws_size >= need) {
        __hip_bfloat16* abt = (__hip_bfloat16*)d_ws;
        hipLaunchKernelGGL(a_permute, dim3((nunits + 255) / 256), dim3(256), 0, stream,
                           inp, abt, nunits);
        hipLaunchKernelGGL((fp8lin_gemm<1>), dim3(grid), dim3(512), 0, stream,
                           inp, (const char*)abt, w, s, out, M);
    } else {
        hipLaunchKernelGGL((fp8lin_gemm<0>), dim3(grid), dim3(512), 0, stream,
                           inp, (const char*)nullptr, w, s, out, M);
    }
}